// Round 2
// baseline (371.338 us; speedup 1.0000x reference)
//
#include <hip/hip_runtime.h>

#define B_ROWS   262144
#define C_DIM    128
#define K_CLS    128
#define PAD_R    2048
#define EPS_F    1e-8f
#define CHUNK    1024
#define G_CHUNKS 256

typedef float f32x4  __attribute__((ext_vector_type(4)));
typedef short bf16x8 __attribute__((ext_vector_type(8)));

__device__ __forceinline__ unsigned f2bf(float f) {
  unsigned u = __float_as_uint(f);
  return (u + 0x7fffu + ((u >> 16) & 1u)) >> 16;   // RNE bf16
}
__device__ __forceinline__ unsigned packbf(float a, float b) {
  return f2bf(a) | (f2bf(b) << 16);
}

// ---------------- histogram over 1024-row chunks ----------------
__global__ __launch_bounds__(256) void hist_kernel(const int* __restrict__ y,
                                                   int* __restrict__ hist) {
  __shared__ int h[K_CLS];
  int g = blockIdx.x, tid = threadIdx.x;
  if (tid < K_CLS) h[tid] = 0;
  __syncthreads();
  for (int j = tid; j < CHUNK; j += 256) atomicAdd(&h[y[g * CHUNK + j]], 1);
  __syncthreads();
  if (tid < K_CLS) hist[g * K_CLS + tid] = h[tid];
}

// ---------------- per-class exclusive scan over chunks ----------------
__global__ __launch_bounds__(256) void scan_kernel(int* __restrict__ hist,
                                                   int* __restrict__ counts) {
  __shared__ int s[G_CHUNKS];
  int k = blockIdx.x, g = threadIdx.x;
  int v = hist[g * K_CLS + k];
  s[g] = v;
  __syncthreads();
  for (int off = 1; off < G_CHUNKS; off <<= 1) {
    int t = (g >= off) ? s[g - off] : 0;
    __syncthreads();
    s[g] += t;
    __syncthreads();
  }
  hist[g * K_CLS + k] = s[g] - v;          // exclusive prefix
  if (g == G_CHUNKS - 1) counts[k] = s[g]; // total count
}

// ---------------- stable ranks -> ord[]; overflow rows -> full-stat atomics ----------------
__global__ __launch_bounds__(256) void rank_kernel(const float* __restrict__ x,
                                                   const int* __restrict__ y,
                                                   const int* __restrict__ hist,
                                                   int* __restrict__ ord,
                                                   float* __restrict__ ovf_sum,
                                                   float* __restrict__ ovf_sq) {
  __shared__ int yl[CHUNK];
  __shared__ unsigned short rk[CHUNK];
  __shared__ int offs[K_CLS];
  int g = blockIdx.x, tid = threadIdx.x;
  for (int j = tid; j < CHUNK; j += 256) yl[j] = y[g * CHUNK + j];
  if (tid < K_CLS) offs[tid] = hist[g * K_CLS + tid];
  __syncthreads();
  if (tid < K_CLS) {           // class-thread sequential stable rank within chunk
    int cnt = 0;
    for (int j = 0; j < CHUNK; ++j)
      if (yl[j] == tid) rk[j] = (unsigned short)(cnt++);
  }
  __syncthreads();
  for (int j = tid; j < CHUNK; j += 256) {
    int k = yl[j];
    int R = offs[k] + (int)rk[j];
    int row = g * CHUNK + j;
    if (R < PAD_R) {
      ord[k * PAD_R + R] = row;
    } else {                   // rare (~2300 rows total): full-stat contribution only
      const f32x4* xr = (const f32x4*)(x + (size_t)row * C_DIM);
      for (int c4 = 0; c4 < C_DIM / 4; ++c4) {
        f32x4 v = xr[c4];
        #pragma unroll
        for (int e = 0; e < 4; ++e) {
          atomicAdd(&ovf_sum[k * C_DIM + c4 * 4 + e], v[e]);
          atomicAdd(&ovf_sq[k * C_DIM + c4 * 4 + e], v[e] * v[e]);
        }
      }
    }
  }
}

// ---------------- per-class X^T X via MFMA, 2 blocks/class ----------------
__global__ __launch_bounds__(512, 1) void gemm_kernel(const float* __restrict__ x,
                                                      const int* __restrict__ ord,
                                                      const int* __restrict__ counts,
                                                      float* __restrict__ spart,
                                                      float* __restrict__ sums_part,
                                                      float* __restrict__ sqs_part) {
  // LDS layout: per tile, 128 c-rows, row stride 36 u32; slot t2 holds bf16 pair (t=2*t2, 2*t2+1)
  __shared__ unsigned int lds[2 * C_DIM * 36]; // 36 KB double-buffered
  const int blk = blockIdx.x;
  const int k = blk >> 1, half = blk & 1;
  const int cnt_full = counts[k];
  const int T = cnt_full < PAD_R ? cnt_full : PAD_R;
  const int nt = (T + 63) >> 6;                // 64-row tiles

  const int tid = threadIdx.x;
  const int lane = tid & 63;
  const int wid = tid >> 6;
  const int q = tid & 15;                      // t-row group: rows 4q..4q+3
  const int c4 = ((tid >> 4) & 31) << 2;       // column chunk base
  const int wr = wid >> 1, wc = wid & 1;       // wave tile: rows wr*32.., cols wc*64..

  f32x4 acc[2][4];
  #pragma unroll
  for (int i = 0; i < 2; ++i)
    #pragma unroll
    for (int j = 0; j < 4; ++j) acc[i][j] = (f32x4){0.f, 0.f, 0.f, 0.f};
  float sum4[4] = {0.f, 0.f, 0.f, 0.f}, sq4[4] = {0.f, 0.f, 0.f, 0.f};

  const int* ordk = ord + k * PAD_R;

  auto load_rows = [&](int r0, f32x4* vv) {
    #pragma unroll
    for (int j = 0; j < 4; ++j) {
      int r = r0 + (q << 2) + j;
      if (r < T) {
        int row = ordk[r];
        vv[j] = *(const f32x4*)(x + (size_t)row * C_DIM + c4);
      } else {
        vv[j] = (f32x4){0.f, 0.f, 0.f, 0.f};
      }
    }
    #pragma unroll
    for (int j = 0; j < 4; ++j)
      #pragma unroll
      for (int e = 0; e < 4; ++e) { float t = vv[j][e]; sum4[e] += t; sq4[e] += t * t; }
  };

  auto write_tile = [&](unsigned int* buf, const f32x4* vv) {
    #pragma unroll
    for (int cc = 0; cc < 4; ++cc) {
      unsigned lo = packbf(vv[0][cc], vv[1][cc]);
      unsigned hi = packbf(vv[2][cc], vv[3][cc]);
      unsigned idx = (unsigned)(c4 + cc) * 36 + (q << 1);
      *(uint2*)(&buf[idx]) = make_uint2(lo, hi);
    }
  };

  auto compute_tile = [&](const unsigned int* buf) {
    #pragma unroll
    for (int s = 0; s < 2; ++s) {              // two K=32 steps per 64-row tile
      const int tslot = (s << 4) + ((lane >> 4) << 2);
      bf16x8 afr[2], bfr[4];
      #pragma unroll
      for (int mi = 0; mi < 2; ++mi) {
        int c = wr * 32 + mi * 16 + (lane & 15);
        afr[mi] = *(const bf16x8*)(&buf[c * 36 + tslot]);
      }
      #pragma unroll
      for (int ni = 0; ni < 4; ++ni) {
        int d = wc * 64 + ni * 16 + (lane & 15);
        bfr[ni] = *(const bf16x8*)(&buf[d * 36 + tslot]);
      }
      #pragma unroll
      for (int mi = 0; mi < 2; ++mi)
        #pragma unroll
        for (int ni = 0; ni < 4; ++ni)
          acc[mi][ni] = __builtin_amdgcn_mfma_f32_16x16x32_bf16(afr[mi], bfr[ni], acc[mi][ni], 0, 0, 0);
    }
  };

  f32x4 v[4];
  if (half < nt) { load_rows(half * 64, v); write_tile(lds, v); }
  __syncthreads();
  int cur = 0;
  for (int tile = half; tile < nt; tile += 2) {
    f32x4 vn[4];
    bool have = (tile + 2) < nt;
    if (have) load_rows((tile + 2) * 64, vn);
    compute_tile(lds + (unsigned)cur * (C_DIM * 36));
    __syncthreads();
    if (have) write_tile(lds + (unsigned)(cur ^ 1) * (C_DIM * 36), vn);
    __syncthreads();
    cur ^= 1;
  }

  // ---- epilogue: reduce truncated sums/sumsq, store partial S ----
  __syncthreads();
  float* red = (float*)lds;
  if (tid < 2 * C_DIM) red[tid] = 0.f;
  __syncthreads();
  #pragma unroll
  for (int e = 0; e < 4; ++e) {
    atomicAdd(&red[c4 + e], sum4[e]);
    atomicAdd(&red[C_DIM + c4 + e], sq4[e]);
  }
  __syncthreads();
  if (tid < C_DIM) {
    sums_part[(half * K_CLS + k) * C_DIM + tid] = red[tid];
    sqs_part[(half * K_CLS + k) * C_DIM + tid] = red[C_DIM + tid];
  }
  float* sp = spart + (size_t)(half * K_CLS + k) * (C_DIM * C_DIM);
  #pragma unroll
  for (int mi = 0; mi < 2; ++mi)
    #pragma unroll
    for (int ni = 0; ni < 4; ++ni)
      #pragma unroll
      for (int r = 0; r < 4; ++r) {
        int c = wr * 32 + mi * 16 + ((lane >> 4) << 2) + r;
        int d = wc * 64 + ni * 16 + (lane & 15);
        sp[c * C_DIM + d] = acc[mi][ni][r];
      }
}

// ---------------- per-class analytic corr, off-diag^2 reduction ----------------
__global__ __launch_bounds__(256) void finalize_kernel(const float* __restrict__ spart,
                                                       const float* __restrict__ sums_part,
                                                       const float* __restrict__ sqs_part,
                                                       const int* __restrict__ counts,
                                                       const float* __restrict__ ovf_sum,
                                                       const float* __restrict__ ovf_sq,
                                                       float* __restrict__ numden) {
  __shared__ float m_l[C_DIM], is_l[C_DIM], st_l[C_DIM];
  __shared__ float wred[4];
  int k = blockIdx.x, tid = threadIdx.x;
  int count = counts[k];
  float Tf = (float)(count < PAD_R ? count : PAD_R);
  if (tid < C_DIM) {
    float s_tr = sums_part[k * C_DIM + tid] + sums_part[(K_CLS + k) * C_DIM + tid];
    float fsum = s_tr + ovf_sum[k * C_DIM + tid];
    float fsq  = sqs_part[k * C_DIM + tid] + sqs_part[(K_CLS + k) * C_DIM + tid]
               + ovf_sq[k * C_DIM + tid];
    float cf = (float)count;
    float m = fsum / fmaxf(cf, 1.f);
    float var = (fsq - cf * m * m) / fmaxf(cf - 1.f, 1.f);
    m_l[tid] = m;
    is_l[tid] = rsqrtf(var + EPS_F);
    st_l[tid] = s_tr;
  }
  __syncthreads();
  const float* S0 = spart + (size_t)k * (C_DIM * C_DIM);
  const float* S1 = spart + (size_t)(K_CLS + k) * (C_DIM * C_DIM);
  float local = 0.f;
  for (int e = tid; e < C_DIM * C_DIM; e += 256) {
    int c = e >> 7, d = e & 127;
    float S = S0[e] + S1[e];
    float corr = is_l[c] * is_l[d] *
                 (S - m_l[c] * st_l[d] - m_l[d] * st_l[c] + Tf * m_l[c] * m_l[d]);
    if (c != d) local += corr * corr;
  }
  for (int off = 32; off > 0; off >>= 1) local += __shfl_down(local, off);
  int lane = tid & 63, wid = tid >> 6;
  if (lane == 0) wred[wid] = local;
  __syncthreads();
  if (tid == 0 && count > 1) {
    float tot = wred[0] + wred[1] + wred[2] + wred[3];
    atomicAdd(&numden[0], tot * (1.f / (float)(C_DIM * (C_DIM - 1))));
    atomicAdd(&numden[1], (float)count);
  }
}

__global__ void div_kernel(const float* __restrict__ numden, float* __restrict__ out) {
  if (threadIdx.x == 0 && blockIdx.x == 0)
    out[0] = numden[1] > 0.f ? numden[0] / numden[1] : 0.f;
}

// ---------------- workspace layout ----------------
// [0,8)        numden (pad to 256)
// [256, +64K)  ovf_sum
// [65792,+64K) ovf_sq
// [131328,+128K) hist
// [262400,+512) counts
// [262912,+1M) ord
// [1311488,+128K) sums_part
// [1442560,+128K) sqs_part
// [1573632,+16M) spart              total ~18.4 MB
extern "C" void kernel_launch(void* const* d_in, const int* in_sizes, int n_in,
                              void* d_out, int out_size, void* d_ws, size_t ws_size,
                              hipStream_t stream) {
  (void)in_sizes; (void)n_in; (void)out_size; (void)ws_size;
  const float* x = (const float*)d_in[0];
  const int*   y = (const int*)d_in[1];
  float* out = (float*)d_out;
  char* ws = (char*)d_ws;

  float* numden    = (float*)(ws + 0);
  float* ovf_sum   = (float*)(ws + 256);
  float* ovf_sq    = (float*)(ws + 256 + 65536);
  int*   hist      = (int*)(ws + 131328);
  int*   counts    = (int*)(ws + 262400);
  int*   ord       = (int*)(ws + 262912);
  float* sums_part = (float*)(ws + 1311488);
  float* sqs_part  = (float*)(ws + 1442560);
  float* spart     = (float*)(ws + 1573632);

  (void)hipMemsetAsync(ws, 0, 131328, stream);  // numden + ovf accumulators

  hist_kernel<<<G_CHUNKS, 256, 0, stream>>>(y, hist);
  scan_kernel<<<K_CLS, 256, 0, stream>>>(hist, counts);
  rank_kernel<<<G_CHUNKS, 256, 0, stream>>>(x, y, hist, ord, ovf_sum, ovf_sq);
  gemm_kernel<<<2 * K_CLS, 512, 0, stream>>>(x, ord, counts, spart, sums_part, sqs_part);
  finalize_kernel<<<K_CLS, 256, 0, stream>>>(spart, sums_part, sqs_part, counts,
                                             ovf_sum, ovf_sq, numden);
  div_kernel<<<1, 64, 0, stream>>>(numden, out);
}

// Round 3
// 304.008 us; speedup vs baseline: 1.2215x; 1.2215x over previous
//
#include <hip/hip_runtime.h>

#define B_ROWS   262144
#define C_DIM    128
#define K_CLS    128
#define PAD_R    2048
#define EPS_F    1e-8f
#define CHUNK    1024
#define G_CHUNKS 256

typedef float f32x4  __attribute__((ext_vector_type(4)));
typedef short bf16x8 __attribute__((ext_vector_type(8)));

__device__ __forceinline__ unsigned f2bf(float f) {
  unsigned u = __float_as_uint(f);
  return (u + 0x7fffu + ((u >> 16) & 1u)) >> 16;   // RNE bf16
}
__device__ __forceinline__ unsigned packbf(float a, float b) {
  return f2bf(a) | (f2bf(b) << 16);
}

// ---------------- histogram over 1024-row chunks ----------------
__global__ __launch_bounds__(256) void hist_kernel(const int* __restrict__ y,
                                                   int* __restrict__ hist) {
  __shared__ int h[K_CLS];
  int g = blockIdx.x, tid = threadIdx.x;
  if (tid < K_CLS) h[tid] = 0;
  __syncthreads();
  for (int j = tid; j < CHUNK; j += 256) atomicAdd(&h[y[g * CHUNK + j]], 1);
  __syncthreads();
  if (tid < K_CLS) hist[g * K_CLS + tid] = h[tid];
}

// ---------------- per-class exclusive scan over chunks ----------------
__global__ __launch_bounds__(256) void scan_kernel(int* __restrict__ hist,
                                                   int* __restrict__ counts) {
  __shared__ int s[G_CHUNKS];
  int k = blockIdx.x, g = threadIdx.x;
  int v = hist[g * K_CLS + k];
  s[g] = v;
  __syncthreads();
  for (int off = 1; off < G_CHUNKS; off <<= 1) {
    int t = (g >= off) ? s[g - off] : 0;
    __syncthreads();
    s[g] += t;
    __syncthreads();
  }
  hist[g * K_CLS + k] = s[g] - v;          // exclusive prefix
  if (g == G_CHUNKS - 1) counts[k] = s[g]; // total count
}

// ---------------- parallel stable ranks -> ord[]; overflow rows -> full-stat atomics ----------------
__global__ __launch_bounds__(256) void rank_kernel(const float* __restrict__ x,
                                                   const int* __restrict__ y,
                                                   const int* __restrict__ hist,
                                                   int* __restrict__ ord,
                                                   float* __restrict__ ovf_sum,
                                                   float* __restrict__ ovf_sq) {
  __shared__ unsigned short cnt_sub[16][K_CLS];  // per-subchunk per-class counts -> prefixes
  __shared__ int offs[K_CLS];
  const int g = blockIdx.x, tid = threadIdx.x;
  const int lane = tid & 63, w = tid >> 6;
  if (tid < K_CLS) offs[tid] = hist[g * K_CLS + tid];
  {
    unsigned int* cz = (unsigned int*)cnt_sub;
    for (int i = tid; i < 16 * K_CLS / 2; i += 256) cz[i] = 0;
  }
  __syncthreads();

  int yv[4], rig[4];
  #pragma unroll
  for (int i = 0; i < 4; ++i) {
    const int s = w * 4 + i;
    const int yy = y[g * CHUNK + s * 64 + lane];
    unsigned long long m = ~0ULL;
    #pragma unroll
    for (int b = 0; b < 7; ++b) {
      unsigned long long bb = __ballot((yy >> b) & 1);
      m &= ((yy >> b) & 1) ? bb : ~bb;
    }
    const unsigned long long lt = (1ULL << lane) - 1ULL;
    rig[i] = (int)__popcll(m & lt);
    yv[i] = yy;
    const int leader = __ffsll((long long)m) - 1;
    if (lane == leader) cnt_sub[s][yy] = (unsigned short)__popcll(m);
  }
  __syncthreads();

  if (tid < K_CLS) {                       // exclusive prefix over 16 subchunks, per class
    int run = 0;
    #pragma unroll
    for (int s = 0; s < 16; ++s) {
      int t = cnt_sub[s][tid];
      cnt_sub[s][tid] = (unsigned short)run;
      run += t;
    }
  }
  __syncthreads();

  #pragma unroll
  for (int i = 0; i < 4; ++i) {
    const int s = w * 4 + i;
    const int k = yv[i];
    const int R = offs[k] + (int)cnt_sub[s][k] + rig[i];
    const int row = g * CHUNK + s * 64 + lane;
    if (R < PAD_R) {
      ord[k * PAD_R + R] = row;
    } else {                               // rare (~2300 rows total): full-stat contribution only
      const f32x4* xr = (const f32x4*)(x + (size_t)row * C_DIM);
      for (int c4 = 0; c4 < C_DIM / 4; ++c4) {
        f32x4 v = xr[c4];
        #pragma unroll
        for (int e = 0; e < 4; ++e) {
          atomicAdd(&ovf_sum[k * C_DIM + c4 * 4 + e], v[e]);
          atomicAdd(&ovf_sq[k * C_DIM + c4 * 4 + e], v[e] * v[e]);
        }
      }
    }
  }
}

// ---------------- per-class X^T X via MFMA, 2 blocks/class ----------------
__global__ __launch_bounds__(512, 1) void gemm_kernel(const float* __restrict__ x,
                                                      const int* __restrict__ ord,
                                                      const int* __restrict__ counts,
                                                      float* __restrict__ spart,
                                                      float* __restrict__ sums_part,
                                                      float* __restrict__ sqs_part) {
  // LDS layout: per tile, 128 c-rows, row stride 36 u32; slot t2 holds bf16 pair (t=2*t2, 2*t2+1)
  __shared__ unsigned int lds[2 * C_DIM * 36]; // 36 KB double-buffered
  const int blk = blockIdx.x;
  const int k = blk >> 1, half = blk & 1;
  const int cnt_full = counts[k];
  const int T = cnt_full < PAD_R ? cnt_full : PAD_R;
  const int nt = (T + 63) >> 6;                // 64-row tiles

  const int tid = threadIdx.x;
  const int lane = tid & 63;
  const int wid = tid >> 6;
  const int q = tid & 15;                      // t-row group: rows 4q..4q+3
  const int c4 = ((tid >> 4) & 31) << 2;       // column chunk base
  const int wr = wid >> 1, wc = wid & 1;       // wave tile: rows wr*32.., cols wc*64..

  f32x4 acc[2][4];
  #pragma unroll
  for (int i = 0; i < 2; ++i)
    #pragma unroll
    for (int j = 0; j < 4; ++j) acc[i][j] = (f32x4){0.f, 0.f, 0.f, 0.f};
  float sum4[4] = {0.f, 0.f, 0.f, 0.f}, sq4[4] = {0.f, 0.f, 0.f, 0.f};

  const int* ordk = ord + k * PAD_R;

  auto load_rows = [&](int r0, f32x4* vv) {
    #pragma unroll
    for (int j = 0; j < 4; ++j) {
      int r = r0 + (q << 2) + j;
      if (r < T) {
        int row = ordk[r];
        vv[j] = *(const f32x4*)(x + (size_t)row * C_DIM + c4);
      } else {
        vv[j] = (f32x4){0.f, 0.f, 0.f, 0.f};
      }
    }
    #pragma unroll
    for (int j = 0; j < 4; ++j)
      #pragma unroll
      for (int e = 0; e < 4; ++e) { float t = vv[j][e]; sum4[e] += t; sq4[e] += t * t; }
  };

  auto write_tile = [&](unsigned int* buf, const f32x4* vv) {
    #pragma unroll
    for (int cc = 0; cc < 4; ++cc) {
      unsigned lo = packbf(vv[0][cc], vv[1][cc]);
      unsigned hi = packbf(vv[2][cc], vv[3][cc]);
      unsigned idx = (unsigned)(c4 + cc) * 36 + (q << 1);
      *(uint2*)(&buf[idx]) = make_uint2(lo, hi);
    }
  };

  auto compute_tile = [&](const unsigned int* buf) {
    #pragma unroll
    for (int s = 0; s < 2; ++s) {              // two K=32 steps per 64-row tile
      const int tslot = (s << 4) + ((lane >> 4) << 2);
      bf16x8 afr[2], bfr[4];
      #pragma unroll
      for (int mi = 0; mi < 2; ++mi) {
        int c = wr * 32 + mi * 16 + (lane & 15);
        afr[mi] = *(const bf16x8*)(&buf[c * 36 + tslot]);
      }
      #pragma unroll
      for (int ni = 0; ni < 4; ++ni) {
        int d = wc * 64 + ni * 16 + (lane & 15);
        bfr[ni] = *(const bf16x8*)(&buf[d * 36 + tslot]);
      }
      #pragma unroll
      for (int mi = 0; mi < 2; ++mi)
        #pragma unroll
        for (int ni = 0; ni < 4; ++ni)
          acc[mi][ni] = __builtin_amdgcn_mfma_f32_16x16x32_bf16(afr[mi], bfr[ni], acc[mi][ni], 0, 0, 0);
    }
  };

  f32x4 v[4];
  if (half < nt) { load_rows(half * 64, v); write_tile(lds, v); }
  __syncthreads();
  int cur = 0;
  for (int tile = half; tile < nt; tile += 2) {
    f32x4 vn[4];
    bool have = (tile + 2) < nt;
    if (have) load_rows((tile + 2) * 64, vn);
    compute_tile(lds + (unsigned)cur * (C_DIM * 36));
    __syncthreads();
    if (have) write_tile(lds + (unsigned)(cur ^ 1) * (C_DIM * 36), vn);
    __syncthreads();
    cur ^= 1;
  }

  // ---- epilogue: reduce truncated sums/sumsq, store partial S ----
  __syncthreads();
  float* red = (float*)lds;
  if (tid < 2 * C_DIM) red[tid] = 0.f;
  __syncthreads();
  #pragma unroll
  for (int e = 0; e < 4; ++e) {
    atomicAdd(&red[c4 + e], sum4[e]);
    atomicAdd(&red[C_DIM + c4 + e], sq4[e]);
  }
  __syncthreads();
  if (tid < C_DIM) {
    sums_part[(half * K_CLS + k) * C_DIM + tid] = red[tid];
    sqs_part[(half * K_CLS + k) * C_DIM + tid] = red[C_DIM + tid];
  }
  float* sp = spart + (size_t)(half * K_CLS + k) * (C_DIM * C_DIM);
  #pragma unroll
  for (int mi = 0; mi < 2; ++mi)
    #pragma unroll
    for (int ni = 0; ni < 4; ++ni)
      #pragma unroll
      for (int r = 0; r < 4; ++r) {
        int c = wr * 32 + mi * 16 + ((lane >> 4) << 2) + r;
        int d = wc * 64 + ni * 16 + (lane & 15);
        sp[c * C_DIM + d] = acc[mi][ni][r];
      }
}

// ---------------- per-class analytic corr, off-diag^2 reduction ----------------
__global__ __launch_bounds__(256) void finalize_kernel(const float* __restrict__ spart,
                                                       const float* __restrict__ sums_part,
                                                       const float* __restrict__ sqs_part,
                                                       const int* __restrict__ counts,
                                                       const float* __restrict__ ovf_sum,
                                                       const float* __restrict__ ovf_sq,
                                                       float* __restrict__ numden) {
  __shared__ float m_l[C_DIM], is_l[C_DIM], st_l[C_DIM];
  __shared__ float wred[4];
  int k = blockIdx.x, tid = threadIdx.x;
  int count = counts[k];
  float Tf = (float)(count < PAD_R ? count : PAD_R);
  if (tid < C_DIM) {
    float s_tr = sums_part[k * C_DIM + tid] + sums_part[(K_CLS + k) * C_DIM + tid];
    float fsum = s_tr + ovf_sum[k * C_DIM + tid];
    float fsq  = sqs_part[k * C_DIM + tid] + sqs_part[(K_CLS + k) * C_DIM + tid]
               + ovf_sq[k * C_DIM + tid];
    float cf = (float)count;
    float m = fsum / fmaxf(cf, 1.f);
    float var = (fsq - cf * m * m) / fmaxf(cf - 1.f, 1.f);
    m_l[tid] = m;
    is_l[tid] = rsqrtf(var + EPS_F);
    st_l[tid] = s_tr;
  }
  __syncthreads();
  const float* S0 = spart + (size_t)k * (C_DIM * C_DIM);
  const float* S1 = spart + (size_t)(K_CLS + k) * (C_DIM * C_DIM);
  float local = 0.f;
  for (int e = tid; e < C_DIM * C_DIM; e += 256) {
    int c = e >> 7, d = e & 127;
    float S = S0[e] + S1[e];
    float corr = is_l[c] * is_l[d] *
                 (S - m_l[c] * st_l[d] - m_l[d] * st_l[c] + Tf * m_l[c] * m_l[d]);
    if (c != d) local += corr * corr;
  }
  for (int off = 32; off > 0; off >>= 1) local += __shfl_down(local, off);
  int lane = tid & 63, wid = tid >> 6;
  if (lane == 0) wred[wid] = local;
  __syncthreads();
  if (tid == 0 && count > 1) {
    float tot = wred[0] + wred[1] + wred[2] + wred[3];
    atomicAdd(&numden[0], tot * (1.f / (float)(C_DIM * (C_DIM - 1))));
    atomicAdd(&numden[1], (float)count);
  }
}

__global__ void div_kernel(const float* __restrict__ numden, float* __restrict__ out) {
  if (threadIdx.x == 0 && blockIdx.x == 0)
    out[0] = numden[1] > 0.f ? numden[0] / numden[1] : 0.f;
}

// ---------------- workspace layout ----------------
extern "C" void kernel_launch(void* const* d_in, const int* in_sizes, int n_in,
                              void* d_out, int out_size, void* d_ws, size_t ws_size,
                              hipStream_t stream) {
  (void)in_sizes; (void)n_in; (void)out_size; (void)ws_size;
  const float* x = (const float*)d_in[0];
  const int*   y = (const int*)d_in[1];
  float* out = (float*)d_out;
  char* ws = (char*)d_ws;

  float* numden    = (float*)(ws + 0);
  float* ovf_sum   = (float*)(ws + 256);
  float* ovf_sq    = (float*)(ws + 256 + 65536);
  int*   hist      = (int*)(ws + 131328);
  int*   counts    = (int*)(ws + 262400);
  int*   ord       = (int*)(ws + 262912);
  float* sums_part = (float*)(ws + 1311488);
  float* sqs_part  = (float*)(ws + 1442560);
  float* spart     = (float*)(ws + 1573632);

  (void)hipMemsetAsync(ws, 0, 131328, stream);  // numden + ovf accumulators

  hist_kernel<<<G_CHUNKS, 256, 0, stream>>>(y, hist);
  scan_kernel<<<K_CLS, 256, 0, stream>>>(hist, counts);
  rank_kernel<<<G_CHUNKS, 256, 0, stream>>>(x, y, hist, ord, ovf_sum, ovf_sq);
  gemm_kernel<<<2 * K_CLS, 512, 0, stream>>>(x, ord, counts, spart, sums_part, sqs_part);
  finalize_kernel<<<K_CLS, 256, 0, stream>>>(spart, sums_part, sqs_part, counts,
                                             ovf_sum, ovf_sq, numden);
  div_kernel<<<1, 64, 0, stream>>>(numden, out);
}

// Round 4
// 104.831 us; speedup vs baseline: 3.5423x; 2.9000x over previous
//
#include <hip/hip_runtime.h>

#define B_ROWS   262144
#define C_DIM    128
#define K_CLS    128
#define PAD_R    2048
#define PAD2     4096
#define EPS_F    1e-8f
#define CHUNK    1024
#define G_CHUNKS 256

typedef float f32x4  __attribute__((ext_vector_type(4)));
typedef short bf16x8 __attribute__((ext_vector_type(8)));

__device__ __forceinline__ unsigned f2bf(float f) {
  unsigned u = __float_as_uint(f);
  return (u + 0x7fffu + ((u >> 16) & 1u)) >> 16;   // RNE bf16
}
__device__ __forceinline__ unsigned packbf(float a, float b) {
  return f2bf(a) | (f2bf(b) << 16);
}

// ---------------- histogram over 1024-row chunks ----------------
__global__ __launch_bounds__(256) void hist_kernel(const int* __restrict__ y,
                                                   int* __restrict__ hist) {
  __shared__ int h[K_CLS];
  int g = blockIdx.x, tid = threadIdx.x;
  if (tid < K_CLS) h[tid] = 0;
  __syncthreads();
  for (int j = tid; j < CHUNK; j += 256) atomicAdd(&h[y[g * CHUNK + j]], 1);
  __syncthreads();
  if (tid < K_CLS) hist[g * K_CLS + tid] = h[tid];
}

// ---------------- per-class exclusive scan over chunks ----------------
__global__ __launch_bounds__(256) void scan_kernel(int* __restrict__ hist,
                                                   int* __restrict__ counts) {
  __shared__ int s[G_CHUNKS];
  int k = blockIdx.x, g = threadIdx.x;
  int v = hist[g * K_CLS + k];
  s[g] = v;
  __syncthreads();
  for (int off = 1; off < G_CHUNKS; off <<= 1) {
    int t = (g >= off) ? s[g - off] : 0;
    __syncthreads();
    s[g] += t;
    __syncthreads();
  }
  hist[g * K_CLS + k] = s[g] - v;          // exclusive prefix
  if (g == G_CHUNKS - 1) counts[k] = s[g]; // total count
}

// ---------------- parallel stable ranks -> ord[] (no atomics, no x) ----------------
__global__ __launch_bounds__(256) void rank_kernel(const int* __restrict__ y,
                                                   const int* __restrict__ hist,
                                                   int* __restrict__ ord) {
  __shared__ unsigned short cnt_sub[16][K_CLS];  // per-subchunk per-class counts -> prefixes
  __shared__ int offs[K_CLS];
  const int g = blockIdx.x, tid = threadIdx.x;
  const int lane = tid & 63, w = tid >> 6;
  if (tid < K_CLS) offs[tid] = hist[g * K_CLS + tid];
  {
    unsigned int* cz = (unsigned int*)cnt_sub;
    for (int i = tid; i < 16 * K_CLS / 2; i += 256) cz[i] = 0;
  }
  __syncthreads();

  int yv[4], rig[4];
  #pragma unroll
  for (int i = 0; i < 4; ++i) {
    const int s = w * 4 + i;
    const int yy = y[g * CHUNK + s * 64 + lane];
    unsigned long long m = ~0ULL;
    #pragma unroll
    for (int b = 0; b < 7; ++b) {
      unsigned long long bb = __ballot((yy >> b) & 1);
      m &= ((yy >> b) & 1) ? bb : ~bb;
    }
    const unsigned long long lt = (1ULL << lane) - 1ULL;
    rig[i] = (int)__popcll(m & lt);
    yv[i] = yy;
    const int leader = __ffsll((long long)m) - 1;
    if (lane == leader) cnt_sub[s][yy] = (unsigned short)__popcll(m);
  }
  __syncthreads();

  if (tid < K_CLS) {                       // exclusive prefix over 16 subchunks, per class
    int run = 0;
    #pragma unroll
    for (int s = 0; s < 16; ++s) {
      int t = cnt_sub[s][tid];
      cnt_sub[s][tid] = (unsigned short)run;
      run += t;
    }
  }
  __syncthreads();

  #pragma unroll
  for (int i = 0; i < 4; ++i) {
    const int s = w * 4 + i;
    const int k = yv[i];
    const int R = offs[k] + (int)cnt_sub[s][k] + rig[i];
    if (R < PAD2) ord[k * PAD2 + R] = g * CHUNK + s * 64 + lane;
  }
}

// ---------------- per-class X^T X via MFMA, 2 blocks/class ----------------
__global__ __launch_bounds__(512, 1) void gemm_kernel(const float* __restrict__ x,
                                                      const int* __restrict__ ord,
                                                      const int* __restrict__ counts,
                                                      float* __restrict__ spart,
                                                      float* __restrict__ sums_part,
                                                      float* __restrict__ sqs_part,
                                                      float* __restrict__ ovfs_part) {
  // LDS layout: per tile, 128 c-rows, row stride 36 u32; slot t2 holds bf16 pair (t=2*t2, 2*t2+1)
  __shared__ unsigned int lds[2 * C_DIM * 36]; // 36 KB double-buffered
  const int blk = blockIdx.x;
  const int k = blk >> 1, half = blk & 1;
  const int cnt_full = counts[k];
  const int T = cnt_full < PAD_R ? cnt_full : PAD_R;
  const int nt = (T + 63) >> 6;                // 64-row tiles

  const int tid = threadIdx.x;
  const int lane = tid & 63;
  const int wid = tid >> 6;
  const int q = tid & 15;                      // t-row group: rows 4q..4q+3
  const int c4 = ((tid >> 4) & 31) << 2;       // column chunk base
  const int wr = wid >> 1, wc = wid & 1;       // wave tile: rows wr*32.., cols wc*64..

  f32x4 acc[2][4];
  #pragma unroll
  for (int i = 0; i < 2; ++i)
    #pragma unroll
    for (int j = 0; j < 4; ++j) acc[i][j] = (f32x4){0.f, 0.f, 0.f, 0.f};
  float sum4[4] = {0.f, 0.f, 0.f, 0.f}, sq4[4] = {0.f, 0.f, 0.f, 0.f};

  const int* ordk = ord + k * PAD2;

  auto load_rows = [&](int r0, f32x4* vv) {
    #pragma unroll
    for (int j = 0; j < 4; ++j) {
      int r = r0 + (q << 2) + j;
      if (r < T) {
        int row = ordk[r];
        vv[j] = *(const f32x4*)(x + (size_t)row * C_DIM + c4);
      } else {
        vv[j] = (f32x4){0.f, 0.f, 0.f, 0.f};
      }
    }
    #pragma unroll
    for (int j = 0; j < 4; ++j)
      #pragma unroll
      for (int e = 0; e < 4; ++e) { float t = vv[j][e]; sum4[e] += t; sq4[e] += t * t; }
  };

  auto write_tile = [&](unsigned int* buf, const f32x4* vv) {
    #pragma unroll
    for (int cc = 0; cc < 4; ++cc) {
      unsigned lo = packbf(vv[0][cc], vv[1][cc]);
      unsigned hi = packbf(vv[2][cc], vv[3][cc]);
      unsigned idx = (unsigned)(c4 + cc) * 36 + (q << 1);
      *(uint2*)(&buf[idx]) = make_uint2(lo, hi);
    }
  };

  auto compute_tile = [&](const unsigned int* buf) {
    #pragma unroll
    for (int s = 0; s < 2; ++s) {              // two K=32 steps per 64-row tile
      const int tslot = (s << 4) + ((lane >> 4) << 2);
      bf16x8 afr[2], bfr[4];
      #pragma unroll
      for (int mi = 0; mi < 2; ++mi) {
        int c = wr * 32 + mi * 16 + (lane & 15);
        afr[mi] = *(const bf16x8*)(&buf[c * 36 + tslot]);
      }
      #pragma unroll
      for (int ni = 0; ni < 4; ++ni) {
        int d = wc * 64 + ni * 16 + (lane & 15);
        bfr[ni] = *(const bf16x8*)(&buf[d * 36 + tslot]);
      }
      #pragma unroll
      for (int mi = 0; mi < 2; ++mi)
        #pragma unroll
        for (int ni = 0; ni < 4; ++ni)
          acc[mi][ni] = __builtin_amdgcn_mfma_f32_16x16x32_bf16(afr[mi], bfr[ni], acc[mi][ni], 0, 0, 0);
    }
  };

  f32x4 v[4];
  if (half < nt) { load_rows(half * 64, v); write_tile(lds, v); }
  __syncthreads();
  int cur = 0;
  for (int tile = half; tile < nt; tile += 2) {
    f32x4 vn[4];
    bool have = (tile + 2) < nt;
    if (have) load_rows((tile + 2) * 64, vn);
    compute_tile(lds + (unsigned)cur * (C_DIM * 36));
    __syncthreads();
    if (have) write_tile(lds + (unsigned)(cur ^ 1) * (C_DIM * 36), vn);
    __syncthreads();
    cur ^= 1;
  }

  // ---- overflow rows (r >= PAD_R): full-stat contribution only, coalesced ----
  float osum[4] = {0.f, 0.f, 0.f, 0.f}, osq[4] = {0.f, 0.f, 0.f, 0.f};
  const int colo = (tid & 31) << 2;
  for (int r = PAD_R + half + ((tid >> 5) << 1); r < cnt_full; r += 32) {
    int row = ordk[r];
    f32x4 vv = *(const f32x4*)(x + (size_t)row * C_DIM + colo);
    #pragma unroll
    for (int e = 0; e < 4; ++e) { float t = vv[e]; osum[e] += t; osq[e] += t * t; }
  }

  // ---- epilogue: reduce trunc-sum / full-sq / ovf-sum, store partial S ----
  __syncthreads();
  float* red = (float*)lds;
  if (tid < 3 * C_DIM) red[tid] = 0.f;
  __syncthreads();
  #pragma unroll
  for (int e = 0; e < 4; ++e) {
    atomicAdd(&red[c4 + e], sum4[e]);
    atomicAdd(&red[C_DIM + c4 + e], sq4[e]);
    atomicAdd(&red[C_DIM + colo + e], osq[e]);
    atomicAdd(&red[2 * C_DIM + colo + e], osum[e]);
  }
  __syncthreads();
  if (tid < C_DIM) {
    sums_part[(half * K_CLS + k) * C_DIM + tid] = red[tid];
    sqs_part [(half * K_CLS + k) * C_DIM + tid] = red[C_DIM + tid];
    ovfs_part[(half * K_CLS + k) * C_DIM + tid] = red[2 * C_DIM + tid];
  }
  float* sp = spart + (size_t)(half * K_CLS + k) * (C_DIM * C_DIM);
  #pragma unroll
  for (int mi = 0; mi < 2; ++mi)
    #pragma unroll
    for (int ni = 0; ni < 4; ++ni)
      #pragma unroll
      for (int r = 0; r < 4; ++r) {
        int c = wr * 32 + mi * 16 + ((lane >> 4) << 2) + r;
        int d = wc * 64 + ni * 16 + (lane & 15);
        sp[c * C_DIM + d] = acc[mi][ni][r];
      }
}

// ---------------- per-class analytic corr, off-diag^2 reduction ----------------
__global__ __launch_bounds__(256) void finalize_kernel(const float* __restrict__ spart,
                                                       const float* __restrict__ sums_part,
                                                       const float* __restrict__ sqs_part,
                                                       const float* __restrict__ ovfs_part,
                                                       const int* __restrict__ counts,
                                                       float* __restrict__ numden) {
  __shared__ float m_l[C_DIM], is_l[C_DIM], st_l[C_DIM];
  __shared__ float wred[4];
  int k = blockIdx.x, tid = threadIdx.x;
  int count = counts[k];
  float Tf = (float)(count < PAD_R ? count : PAD_R);
  if (tid < C_DIM) {
    float s_tr = sums_part[k * C_DIM + tid] + sums_part[(K_CLS + k) * C_DIM + tid];
    float osum = ovfs_part[k * C_DIM + tid] + ovfs_part[(K_CLS + k) * C_DIM + tid];
    float fsum = s_tr + osum;
    float fsq  = sqs_part[k * C_DIM + tid] + sqs_part[(K_CLS + k) * C_DIM + tid];
    float cf = (float)count;
    float m = fsum / fmaxf(cf, 1.f);
    float var = (fsq - cf * m * m) / fmaxf(cf - 1.f, 1.f);
    m_l[tid] = m;
    is_l[tid] = rsqrtf(var + EPS_F);
    st_l[tid] = s_tr;
  }
  __syncthreads();
  const float* S0 = spart + (size_t)k * (C_DIM * C_DIM);
  const float* S1 = spart + (size_t)(K_CLS + k) * (C_DIM * C_DIM);
  float local = 0.f;
  for (int e = tid; e < C_DIM * C_DIM; e += 256) {
    int c = e >> 7, d = e & 127;
    float S = S0[e] + S1[e];
    float corr = is_l[c] * is_l[d] *
                 (S - m_l[c] * st_l[d] - m_l[d] * st_l[c] + Tf * m_l[c] * m_l[d]);
    if (c != d) local += corr * corr;
  }
  for (int off = 32; off > 0; off >>= 1) local += __shfl_down(local, off);
  int lane = tid & 63, wid = tid >> 6;
  if (lane == 0) wred[wid] = local;
  __syncthreads();
  if (tid == 0 && count > 1) {
    float tot = wred[0] + wred[1] + wred[2] + wred[3];
    atomicAdd(&numden[0], tot * (1.f / (float)(C_DIM * (C_DIM - 1))));
    atomicAdd(&numden[1], (float)count);
  }
}

__global__ void div_kernel(const float* __restrict__ numden, float* __restrict__ out) {
  if (threadIdx.x == 0 && blockIdx.x == 0)
    out[0] = numden[1] > 0.f ? numden[0] / numden[1] : 0.f;
}

// ---------------- workspace layout ----------------
// [0,256)            numden
// [256, +128K)       hist
// [131328, +512)     counts
// [132096, +2M)      ord (128 * 4096 * 4)
// [2229248, +128K)   sums_part
// [2360320, +128K)   sqs_part
// [2491392, +128K)   ovfs_part
// [2622464, +16M)    spart           total ~19.4 MB
extern "C" void kernel_launch(void* const* d_in, const int* in_sizes, int n_in,
                              void* d_out, int out_size, void* d_ws, size_t ws_size,
                              hipStream_t stream) {
  (void)in_sizes; (void)n_in; (void)out_size; (void)ws_size;
  const float* x = (const float*)d_in[0];
  const int*   y = (const int*)d_in[1];
  float* out = (float*)d_out;
  char* ws = (char*)d_ws;

  float* numden    = (float*)(ws + 0);
  int*   hist      = (int*)(ws + 256);
  int*   counts    = (int*)(ws + 131328);
  int*   ord       = (int*)(ws + 132096);
  float* sums_part = (float*)(ws + 2229248);
  float* sqs_part  = (float*)(ws + 2360320);
  float* ovfs_part = (float*)(ws + 2491392);
  float* spart     = (float*)(ws + 2622464);

  (void)hipMemsetAsync(numden, 0, 256, stream);

  hist_kernel<<<G_CHUNKS, 256, 0, stream>>>(y, hist);
  scan_kernel<<<K_CLS, 256, 0, stream>>>(hist, counts);
  rank_kernel<<<G_CHUNKS, 256, 0, stream>>>(y, hist, ord);
  gemm_kernel<<<2 * K_CLS, 512, 0, stream>>>(x, ord, counts, spart, sums_part, sqs_part,
                                             ovfs_part);
  finalize_kernel<<<K_CLS, 256, 0, stream>>>(spart, sums_part, sqs_part, ovfs_part,
                                             counts, numden);
  div_kernel<<<1, 64, 0, stream>>>(numden, out);
}

// Round 5
// 85.347 us; speedup vs baseline: 4.3509x; 1.2283x over previous
//
#include <hip/hip_runtime.h>

#define B_ROWS   262144
#define C_DIM    128
#define K_CLS    128
#define PAD_R    2048
#define PAD2     4096
#define EPS_F    1e-8f
#define CHUNK    1024
#define G_CHUNKS 256

typedef float f32x4  __attribute__((ext_vector_type(4)));
typedef short bf16x8 __attribute__((ext_vector_type(8)));

__device__ __forceinline__ unsigned f2bf(float f) {
  unsigned u = __float_as_uint(f);
  return (u + 0x7fffu + ((u >> 16) & 1u)) >> 16;   // RNE bf16
}
__device__ __forceinline__ unsigned packbf(float a, float b) {
  return f2bf(a) | (f2bf(b) << 16);
}
__device__ __forceinline__ int swzkey(int c) { return (c ^ (c >> 2)) & 7; }

// ---------------- histogram over 1024-row chunks ----------------
__global__ __launch_bounds__(256) void hist_kernel(const int* __restrict__ y,
                                                   int* __restrict__ hist) {
  __shared__ int h[K_CLS];
  int g = blockIdx.x, tid = threadIdx.x;
  if (tid < K_CLS) h[tid] = 0;
  __syncthreads();
  for (int j = tid; j < CHUNK; j += 256) atomicAdd(&h[y[g * CHUNK + j]], 1);
  __syncthreads();
  if (tid < K_CLS) hist[g * K_CLS + tid] = h[tid];
}

// ---------------- per-class exclusive scan over chunks ----------------
__global__ __launch_bounds__(256) void scan_kernel(int* __restrict__ hist,
                                                   int* __restrict__ counts) {
  __shared__ int s[G_CHUNKS];
  int k = blockIdx.x, g = threadIdx.x;
  int v = hist[g * K_CLS + k];
  s[g] = v;
  __syncthreads();
  for (int off = 1; off < G_CHUNKS; off <<= 1) {
    int t = (g >= off) ? s[g - off] : 0;
    __syncthreads();
    s[g] += t;
    __syncthreads();
  }
  hist[g * K_CLS + k] = s[g] - v;          // exclusive prefix
  if (g == G_CHUNKS - 1) counts[k] = s[g]; // total count
}

// ---------------- parallel stable ranks -> ord[] (no atomics, no x) ----------------
__global__ __launch_bounds__(256) void rank_kernel(const int* __restrict__ y,
                                                   const int* __restrict__ hist,
                                                   int* __restrict__ ord) {
  __shared__ unsigned short cnt_sub[16][K_CLS];  // per-subchunk per-class counts -> prefixes
  __shared__ int offs[K_CLS];
  const int g = blockIdx.x, tid = threadIdx.x;
  const int lane = tid & 63, w = tid >> 6;
  if (tid < K_CLS) offs[tid] = hist[g * K_CLS + tid];
  {
    unsigned int* cz = (unsigned int*)cnt_sub;
    for (int i = tid; i < 16 * K_CLS / 2; i += 256) cz[i] = 0;
  }
  __syncthreads();

  int yv[4], rig[4];
  #pragma unroll
  for (int i = 0; i < 4; ++i) {
    const int s = w * 4 + i;
    const int yy = y[g * CHUNK + s * 64 + lane];
    unsigned long long m = ~0ULL;
    #pragma unroll
    for (int b = 0; b < 7; ++b) {
      unsigned long long bb = __ballot((yy >> b) & 1);
      m &= ((yy >> b) & 1) ? bb : ~bb;
    }
    const unsigned long long lt = (1ULL << lane) - 1ULL;
    rig[i] = (int)__popcll(m & lt);
    yv[i] = yy;
    const int leader = __ffsll((long long)m) - 1;
    if (lane == leader) cnt_sub[s][yy] = (unsigned short)__popcll(m);
  }
  __syncthreads();

  if (tid < K_CLS) {                       // exclusive prefix over 16 subchunks, per class
    int run = 0;
    #pragma unroll
    for (int s = 0; s < 16; ++s) {
      int t = cnt_sub[s][tid];
      cnt_sub[s][tid] = (unsigned short)run;
      run += t;
    }
  }
  __syncthreads();

  #pragma unroll
  for (int i = 0; i < 4; ++i) {
    const int s = w * 4 + i;
    const int k = yv[i];
    const int R = offs[k] + (int)cnt_sub[s][k] + rig[i];
    if (R < PAD2) ord[k * PAD2 + R] = g * CHUNK + s * 64 + lane;
  }
}

// ---------------- per-class X^T X via MFMA, 2 blocks/class ----------------
// LDS per buffer: 128 c-rows x 32 u32 (t-pairs), XOR-swizzled in 16B groups:
//   addr_u32(c,u) = c*32 + (((u>>2) ^ swzkey(c)) << 2 | (u&3))
__global__ __launch_bounds__(512, 1) void gemm_kernel(const float* __restrict__ x,
                                                      const int* __restrict__ ord,
                                                      const int* __restrict__ counts,
                                                      float* __restrict__ spart,
                                                      float* __restrict__ sums_part,
                                                      float* __restrict__ sqs_part,
                                                      float* __restrict__ ovfs_part) {
  __shared__ unsigned int lds[2 * C_DIM * 32];   // 32 KB double-buffered
  const int blk = blockIdx.x;
  const int k = blk >> 1, half = blk & 1;
  const int cnt_full = counts[k];
  const int T = cnt_full < PAD_R ? cnt_full : PAD_R;
  const int r_base = half * (PAD_R / 2);
  const int rend = (T < r_base + PAD_R / 2) ? T : (r_base + PAD_R / 2);
  const int nt = (rend > r_base) ? ((rend - r_base + 63) >> 6) : 0;

  const int tid = threadIdx.x;
  const int lane = tid & 63;
  const int w = tid >> 6;                  // wave 0..7
  const int wr = w >> 1, wc = w & 1;       // wave tile: rows wr*32.., cols wc*64..
  const int l5 = lane >> 5;                // half-wave: row pair select
  const int lc = lane & 31;                // 16B column slice

  f32x4 acc[2][4];
  #pragma unroll
  for (int i = 0; i < 2; ++i)
    #pragma unroll
    for (int j = 0; j < 4; ++j) acc[i][j] = (f32x4){0.f, 0.f, 0.f, 0.f};
  float sum4[4] = {0.f, 0.f, 0.f, 0.f}, sq4[4] = {0.f, 0.f, 0.f, 0.f};

  const int* ordk = ord + k * PAD2;

  // per tile, this lane loads rows (base, base+1) with base = r0 + w*8 + 4*jp + 2*l5,
  // cols 4*lc..4*lc+3. vv[jp*2+b] = row base+b.
  auto load_tile = [&](int r0, f32x4* vv) {
    #pragma unroll
    for (int jp = 0; jp < 2; ++jp) {
      const int rA = r0 + w * 8 + 4 * jp + 2 * l5;
      #pragma unroll
      for (int b = 0; b < 2; ++b) {
        const int r = rA + b;
        if (r < rend) {
          const int row = ordk[r];
          vv[jp * 2 + b] = *(const f32x4*)(x + (size_t)row * C_DIM + (lc << 2));
        } else {
          vv[jp * 2 + b] = (f32x4){0.f, 0.f, 0.f, 0.f};
        }
      }
    }
    #pragma unroll
    for (int j = 0; j < 4; ++j)
      #pragma unroll
      for (int e = 0; e < 4; ++e) { float t = vv[j][e]; sum4[e] += t; sq4[e] += t * t; }
  };

  auto write_tile = [&](unsigned int* buf, const f32x4* vv) {
    #pragma unroll
    for (int jp = 0; jp < 2; ++jp) {
      const int u = w * 4 + 2 * jp + l5;   // u>>2 == w
      const int us = u & 3;
      #pragma unroll
      for (int e = 0; e < 4; ++e) {
        const int c = (lc << 2) + e;
        buf[c * 32 + (((w ^ swzkey(c)) << 2) | us)] =
            packbf(vv[jp * 2][e], vv[jp * 2 + 1][e]);
      }
    }
  };

  auto compute_tile = [&](const unsigned int* buf) {
    const int q2 = lane >> 4;              // k-sub group
    const int fr = lane & 15;              // fragment row/col
    #pragma unroll
    for (int s = 0; s < 2; ++s) {          // two K=32 steps per 64-row tile
      const int g = s * 4 + q2;
      bf16x8 afr[2], bfr[4];
      #pragma unroll
      for (int mi = 0; mi < 2; ++mi) {
        const int c = wr * 32 + mi * 16 + fr;
        afr[mi] = *(const bf16x8*)(&buf[c * 32 + ((g ^ swzkey(c)) << 2)]);
      }
      #pragma unroll
      for (int ni = 0; ni < 4; ++ni) {
        const int d = wc * 64 + ni * 16 + fr;
        bfr[ni] = *(const bf16x8*)(&buf[d * 32 + ((g ^ swzkey(d)) << 2)]);
      }
      #pragma unroll
      for (int mi = 0; mi < 2; ++mi)
        #pragma unroll
        for (int ni = 0; ni < 4; ++ni)
          acc[mi][ni] = __builtin_amdgcn_mfma_f32_16x16x32_bf16(afr[mi], bfr[ni], acc[mi][ni], 0, 0, 0);
    }
  };

  f32x4 v[4];
  if (nt > 0) { load_tile(r_base, v); write_tile(lds, v); }
  __syncthreads();
  int cur = 0;
  for (int t = 0; t < nt; ++t) {
    f32x4 vn[4];
    const bool have = (t + 1) < nt;
    if (have) load_tile(r_base + (t + 1) * 64, vn);
    compute_tile(lds + (unsigned)cur * (C_DIM * 32));
    __syncthreads();
    if (have) write_tile(lds + (unsigned)(cur ^ 1) * (C_DIM * 32), vn);
    __syncthreads();
    cur ^= 1;
  }

  // ---- overflow rows (r >= PAD_R): full-stat contribution only, coalesced ----
  float osum[4] = {0.f, 0.f, 0.f, 0.f}, osq[4] = {0.f, 0.f, 0.f, 0.f};
  const int colo = lc << 2;
  for (int r = PAD_R + half + ((tid >> 5) << 1); r < cnt_full; r += 32) {
    int row = ordk[r];
    f32x4 vv = *(const f32x4*)(x + (size_t)row * C_DIM + colo);
    #pragma unroll
    for (int e = 0; e < 4; ++e) { float t = vv[e]; osum[e] += t; osq[e] += t * t; }
  }

  // ---- epilogue: reduce trunc-sum / full-sq / ovf-sum, store partial S ----
  __syncthreads();
  float* red = (float*)lds;
  if (tid < 3 * C_DIM) red[tid] = 0.f;
  __syncthreads();
  #pragma unroll
  for (int e = 0; e < 4; ++e) {
    atomicAdd(&red[colo + e], sum4[e]);
    atomicAdd(&red[C_DIM + colo + e], sq4[e] + osq[e]);
    atomicAdd(&red[2 * C_DIM + colo + e], osum[e]);
  }
  __syncthreads();
  if (tid < C_DIM) {
    sums_part[(half * K_CLS + k) * C_DIM + tid] = red[tid];
    sqs_part [(half * K_CLS + k) * C_DIM + tid] = red[C_DIM + tid];
    ovfs_part[(half * K_CLS + k) * C_DIM + tid] = red[2 * C_DIM + tid];
  }
  float* sp = spart + (size_t)(half * K_CLS + k) * (C_DIM * C_DIM);
  #pragma unroll
  for (int mi = 0; mi < 2; ++mi)
    #pragma unroll
    for (int ni = 0; ni < 4; ++ni)
      #pragma unroll
      for (int r = 0; r < 4; ++r) {
        int c = wr * 32 + mi * 16 + ((lane >> 4) << 2) + r;
        int d = wc * 64 + ni * 16 + (lane & 15);
        sp[c * C_DIM + d] = acc[mi][ni][r];
      }
}

// ---------------- per-class analytic corr, off-diag^2 reduction ----------------
__global__ __launch_bounds__(512) void finalize_kernel(const float* __restrict__ spart,
                                                       const float* __restrict__ sums_part,
                                                       const float* __restrict__ sqs_part,
                                                       const float* __restrict__ ovfs_part,
                                                       const int* __restrict__ counts,
                                                       float* __restrict__ numden) {
  __shared__ float m_l[C_DIM], is_l[C_DIM], st_l[C_DIM];
  __shared__ float wred[8];
  int k = blockIdx.x, tid = threadIdx.x;
  int count = counts[k];
  float Tf = (float)(count < PAD_R ? count : PAD_R);
  if (tid < C_DIM) {
    float s_tr = sums_part[k * C_DIM + tid] + sums_part[(K_CLS + k) * C_DIM + tid];
    float osum = ovfs_part[k * C_DIM + tid] + ovfs_part[(K_CLS + k) * C_DIM + tid];
    float fsum = s_tr + osum;
    float fsq  = sqs_part[k * C_DIM + tid] + sqs_part[(K_CLS + k) * C_DIM + tid];
    float cf = (float)count;
    float m = fsum / fmaxf(cf, 1.f);
    float var = (fsq - cf * m * m) / fmaxf(cf - 1.f, 1.f);
    m_l[tid] = m;
    is_l[tid] = rsqrtf(var + EPS_F);
    st_l[tid] = s_tr;
  }
  __syncthreads();
  const float* S0 = spart + (size_t)k * (C_DIM * C_DIM);
  const float* S1 = spart + (size_t)(K_CLS + k) * (C_DIM * C_DIM);
  float local = 0.f;
  for (int e4 = tid * 4; e4 < C_DIM * C_DIM; e4 += 512 * 4) {
    int c = e4 >> 7, d0 = e4 & 127;
    f32x4 s0 = *(const f32x4*)(S0 + e4);
    f32x4 s1 = *(const f32x4*)(S1 + e4);
    #pragma unroll
    for (int e = 0; e < 4; ++e) {
      int d = d0 + e;
      float S = s0[e] + s1[e];
      float corr = is_l[c] * is_l[d] *
                   (S - m_l[c] * st_l[d] - m_l[d] * st_l[c] + Tf * m_l[c] * m_l[d]);
      if (c != d) local += corr * corr;
    }
  }
  for (int off = 32; off > 0; off >>= 1) local += __shfl_down(local, off);
  int lane = tid & 63, wid = tid >> 6;
  if (lane == 0) wred[wid] = local;
  __syncthreads();
  if (tid == 0 && count > 1) {
    float tot = 0.f;
    #pragma unroll
    for (int i = 0; i < 8; ++i) tot += wred[i];
    atomicAdd(&numden[0], tot * (1.f / (float)(C_DIM * (C_DIM - 1))));
    atomicAdd(&numden[1], (float)count);
  }
}

__global__ void div_kernel(const float* __restrict__ numden, float* __restrict__ out) {
  if (threadIdx.x == 0 && blockIdx.x == 0)
    out[0] = numden[1] > 0.f ? numden[0] / numden[1] : 0.f;
}

// ---------------- workspace layout ----------------
// [0,256)            numden
// [256, +128K)       hist
// [131328, +512)     counts
// [132096, +2M)      ord (128 * 4096 * 4)
// [2229248, +128K)   sums_part
// [2360320, +128K)   sqs_part
// [2491392, +128K)   ovfs_part
// [2622464, +16M)    spart           total ~19.4 MB
extern "C" void kernel_launch(void* const* d_in, const int* in_sizes, int n_in,
                              void* d_out, int out_size, void* d_ws, size_t ws_size,
                              hipStream_t stream) {
  (void)in_sizes; (void)n_in; (void)out_size; (void)ws_size;
  const float* x = (const float*)d_in[0];
  const int*   y = (const int*)d_in[1];
  float* out = (float*)d_out;
  char* ws = (char*)d_ws;

  float* numden    = (float*)(ws + 0);
  int*   hist      = (int*)(ws + 256);
  int*   counts    = (int*)(ws + 131328);
  int*   ord       = (int*)(ws + 132096);
  float* sums_part = (float*)(ws + 2229248);
  float* sqs_part  = (float*)(ws + 2360320);
  float* ovfs_part = (float*)(ws + 2491392);
  float* spart     = (float*)(ws + 2622464);

  (void)hipMemsetAsync(numden, 0, 256, stream);

  hist_kernel<<<G_CHUNKS, 256, 0, stream>>>(y, hist);
  scan_kernel<<<K_CLS, 256, 0, stream>>>(hist, counts);
  rank_kernel<<<G_CHUNKS, 256, 0, stream>>>(y, hist, ord);
  gemm_kernel<<<2 * K_CLS, 512, 0, stream>>>(x, ord, counts, spart, sums_part, sqs_part,
                                             ovfs_part);
  finalize_kernel<<<K_CLS, 512, 0, stream>>>(spart, sums_part, sqs_part, ovfs_part,
                                             counts, numden);
  div_kernel<<<1, 64, 0, stream>>>(numden, out);
}

// Round 6
// 64.960 us; speedup vs baseline: 5.7164x; 1.3138x over previous
//
#include <hip/hip_runtime.h>

#define B_ROWS   262144
#define C_DIM    128
#define K_CLS    128
#define PAD_R    2048
#define PAD2     4096
#define EPS_F    1e-8f
#define CHUNK    1024
#define G_CHUNKS 256

typedef float f32x4  __attribute__((ext_vector_type(4)));
typedef short bf16x8 __attribute__((ext_vector_type(8)));

__device__ __forceinline__ unsigned f2bf(float f) {
  unsigned u = __float_as_uint(f);
  return (u + 0x7fffu + ((u >> 16) & 1u)) >> 16;   // RNE bf16
}
__device__ __forceinline__ unsigned packbf(float a, float b) {
  return f2bf(a) | (f2bf(b) << 16);
}
__device__ __forceinline__ int swzkey(int c) { return (c ^ (c >> 2)) & 7; }

// ---------------- histogram over 1024-row chunks ----------------
__global__ __launch_bounds__(256) void hist_kernel(const int* __restrict__ y,
                                                   int* __restrict__ hist) {
  __shared__ int h[K_CLS];
  int g = blockIdx.x, tid = threadIdx.x;
  if (tid < K_CLS) h[tid] = 0;
  __syncthreads();
  for (int j = tid; j < CHUNK; j += 256) atomicAdd(&h[y[g * CHUNK + j]], 1);
  __syncthreads();
  if (tid < K_CLS) hist[g * K_CLS + tid] = h[tid];
}

// ---------------- per-class exclusive scan over chunks ----------------
__global__ __launch_bounds__(256) void scan_kernel(int* __restrict__ hist,
                                                   int* __restrict__ counts) {
  __shared__ int s[G_CHUNKS];
  int k = blockIdx.x, g = threadIdx.x;
  int v = hist[g * K_CLS + k];
  s[g] = v;
  __syncthreads();
  for (int off = 1; off < G_CHUNKS; off <<= 1) {
    int t = (g >= off) ? s[g - off] : 0;
    __syncthreads();
    s[g] += t;
    __syncthreads();
  }
  hist[g * K_CLS + k] = s[g] - v;          // exclusive prefix
  if (g == G_CHUNKS - 1) counts[k] = s[g]; // total count
}

// ---------------- parallel stable ranks -> ord[] (no atomics, no x) ----------------
__global__ __launch_bounds__(256) void rank_kernel(const int* __restrict__ y,
                                                   const int* __restrict__ hist,
                                                   int* __restrict__ ord) {
  __shared__ unsigned short cnt_sub[16][K_CLS];  // per-subchunk per-class counts -> prefixes
  __shared__ int offs[K_CLS];
  const int g = blockIdx.x, tid = threadIdx.x;
  const int lane = tid & 63, w = tid >> 6;
  if (tid < K_CLS) offs[tid] = hist[g * K_CLS + tid];
  {
    unsigned int* cz = (unsigned int*)cnt_sub;
    for (int i = tid; i < 16 * K_CLS / 2; i += 256) cz[i] = 0;
  }
  __syncthreads();

  int yv[4], rig[4];
  #pragma unroll
  for (int i = 0; i < 4; ++i) {
    const int s = w * 4 + i;
    const int yy = y[g * CHUNK + s * 64 + lane];
    unsigned long long m = ~0ULL;
    #pragma unroll
    for (int b = 0; b < 7; ++b) {
      unsigned long long bb = __ballot((yy >> b) & 1);
      m &= ((yy >> b) & 1) ? bb : ~bb;
    }
    const unsigned long long lt = (1ULL << lane) - 1ULL;
    rig[i] = (int)__popcll(m & lt);
    yv[i] = yy;
    const int leader = __ffsll((long long)m) - 1;
    if (lane == leader) cnt_sub[s][yy] = (unsigned short)__popcll(m);
  }
  __syncthreads();

  if (tid < K_CLS) {                       // exclusive prefix over 16 subchunks, per class
    int run = 0;
    #pragma unroll
    for (int s = 0; s < 16; ++s) {
      int t = cnt_sub[s][tid];
      cnt_sub[s][tid] = (unsigned short)run;
      run += t;
    }
  }
  __syncthreads();

  #pragma unroll
  for (int i = 0; i < 4; ++i) {
    const int s = w * 4 + i;
    const int k = yv[i];
    const int R = offs[k] + (int)cnt_sub[s][k] + rig[i];
    if (R < PAD2) ord[k * PAD2 + R] = g * CHUNK + s * 64 + lane;
  }
}

// ---------------- per-class X^T X via MFMA, 2 blocks/class ----------------
// LDS tile buffer: 128 c-rows x 32 u32 (t-pairs), XOR-swizzled in 16B groups:
//   addr_u32(c,u) = c*32 + (((u>>2) ^ swzkey(c)) << 2 | (u&3))
// ord indices staged in LDS once; lane's 4 rows contiguous -> one ds_read_b128
// for indices, then 4 independent x loads (no global->global dependency).
__global__ __launch_bounds__(512, 1) void gemm_kernel(const float* __restrict__ x,
                                                      const int* __restrict__ ord,
                                                      const int* __restrict__ counts,
                                                      float* __restrict__ spart,
                                                      float* __restrict__ sums_part,
                                                      float* __restrict__ sqs_part,
                                                      float* __restrict__ ovfs_part) {
  __shared__ unsigned int lds[2 * C_DIM * 32];   // 32 KB double-buffered
  __shared__ int ord_l[PAD_R / 2];               // 4 KB staged indices
  const int blk = blockIdx.x;
  const int k = blk >> 1, half = blk & 1;
  const int cnt_full = counts[k];
  const int T = cnt_full < PAD_R ? cnt_full : PAD_R;
  const int r_base = half * (PAD_R / 2);
  const int rend = (T < r_base + PAD_R / 2) ? T : (r_base + PAD_R / 2);
  const int nr = rend - r_base;
  const int nt = (nr > 0) ? ((nr + 63) >> 6) : 0;

  const int tid = threadIdx.x;
  const int lane = tid & 63;
  const int w = tid >> 6;                  // wave 0..7
  const int wr = w >> 1, wc = w & 1;       // wave tile: rows wr*32.., cols wc*64..
  const int l5 = lane >> 5;                // half-wave select
  const int lc = lane & 31;                // 16B column slice

  f32x4 acc[2][4];
  #pragma unroll
  for (int i = 0; i < 2; ++i)
    #pragma unroll
    for (int j = 0; j < 4; ++j) acc[i][j] = (f32x4){0.f, 0.f, 0.f, 0.f};
  float sum4[4] = {0.f, 0.f, 0.f, 0.f}, sq4[4] = {0.f, 0.f, 0.f, 0.f};

  const int* ordk = ord + k * PAD2;

  for (int i = tid; i < PAD_R / 2; i += 512) ord_l[i] = ordk[r_base + i];
  __syncthreads();

  // lane's quartet for tile t: local rows rr..rr+3, rr = t*64 + w*8 + l5*4
  auto load_tile = [&](int t, f32x4* vv) {
    const int rr = t * 64 + w * 8 + l5 * 4;
    const int4 idx = *(const int4*)(&ord_l[rr]);
    const int rg = r_base + rr;
    const size_t co = (size_t)(lc << 2);
    const f32x4 z = (f32x4){0.f, 0.f, 0.f, 0.f};
    vv[0] = (rg + 0 < rend) ? *(const f32x4*)(x + (size_t)idx.x * C_DIM + co) : z;
    vv[1] = (rg + 1 < rend) ? *(const f32x4*)(x + (size_t)idx.y * C_DIM + co) : z;
    vv[2] = (rg + 2 < rend) ? *(const f32x4*)(x + (size_t)idx.z * C_DIM + co) : z;
    vv[3] = (rg + 3 < rend) ? *(const f32x4*)(x + (size_t)idx.w * C_DIM + co) : z;
  };

  // stats + pack into LDS; pair index u = w*4 + l5*2 + jp  (u>>2 == w)
  auto write_tile = [&](unsigned int* buf, const f32x4* vv) {
    #pragma unroll
    for (int j = 0; j < 4; ++j)
      #pragma unroll
      for (int e = 0; e < 4; ++e) { float t = vv[j][e]; sum4[e] += t; sq4[e] += t * t; }
    #pragma unroll
    for (int jp = 0; jp < 2; ++jp) {
      const int us = l5 * 2 + jp;
      #pragma unroll
      for (int e = 0; e < 4; ++e) {
        const int c = (lc << 2) + e;
        buf[c * 32 + (((w ^ swzkey(c)) << 2) | us)] =
            packbf(vv[jp * 2][e], vv[jp * 2 + 1][e]);
      }
    }
  };

  auto compute_tile = [&](const unsigned int* buf) {
    const int q2 = lane >> 4;
    const int fr = lane & 15;
    #pragma unroll
    for (int s = 0; s < 2; ++s) {          // two K=32 steps per 64-row tile
      const int g = s * 4 + q2;
      bf16x8 afr[2], bfr[4];
      #pragma unroll
      for (int mi = 0; mi < 2; ++mi) {
        const int c = wr * 32 + mi * 16 + fr;
        afr[mi] = *(const bf16x8*)(&buf[c * 32 + ((g ^ swzkey(c)) << 2)]);
      }
      #pragma unroll
      for (int ni = 0; ni < 4; ++ni) {
        const int d = wc * 64 + ni * 16 + fr;
        bfr[ni] = *(const bf16x8*)(&buf[d * 32 + ((g ^ swzkey(d)) << 2)]);
      }
      #pragma unroll
      for (int mi = 0; mi < 2; ++mi)
        #pragma unroll
        for (int ni = 0; ni < 4; ++ni)
          acc[mi][ni] = __builtin_amdgcn_mfma_f32_16x16x32_bf16(afr[mi], bfr[ni], acc[mi][ni], 0, 0, 0);
    }
  };

  // software pipeline: 1 barrier/tile, loads issued 2 tiles ahead, unroll x2
  f32x4 va[4], vb[4];
  if (nt > 0) { load_tile(0, va); write_tile(lds, va); }
  if (nt > 1) load_tile(1, va);
  __syncthreads();
  int cur = 0;
  for (int t = 0; t < nt; t += 2) {
    if (t + 1 < nt) write_tile(lds + (unsigned)(cur ^ 1) * (C_DIM * 32), va);
    if (t + 2 < nt) load_tile(t + 2, vb);
    compute_tile(lds + (unsigned)cur * (C_DIM * 32));
    __syncthreads();
    cur ^= 1;
    if (t + 1 >= nt) break;
    if (t + 2 < nt) write_tile(lds + (unsigned)(cur ^ 1) * (C_DIM * 32), vb);
    if (t + 3 < nt) load_tile(t + 3, va);
    compute_tile(lds + (unsigned)cur * (C_DIM * 32));
    __syncthreads();
    cur ^= 1;
  }

  // ---- overflow rows (r >= PAD_R): full-stat contribution only, coalesced ----
  float osum[4] = {0.f, 0.f, 0.f, 0.f}, osq[4] = {0.f, 0.f, 0.f, 0.f};
  const int colo = lc << 2;
  for (int r = PAD_R + half + ((tid >> 5) << 1); r < cnt_full; r += 32) {
    int row = ordk[r];
    f32x4 vv = *(const f32x4*)(x + (size_t)row * C_DIM + colo);
    #pragma unroll
    for (int e = 0; e < 4; ++e) { float t = vv[e]; osum[e] += t; osq[e] += t * t; }
  }

  // ---- epilogue: reduce trunc-sum / full-sq / ovf-sum, store partial S ----
  __syncthreads();
  float* red = (float*)lds;
  if (tid < 3 * C_DIM) red[tid] = 0.f;
  __syncthreads();
  #pragma unroll
  for (int e = 0; e < 4; ++e) {
    atomicAdd(&red[colo + e], sum4[e]);
    atomicAdd(&red[C_DIM + colo + e], sq4[e] + osq[e]);
    atomicAdd(&red[2 * C_DIM + colo + e], osum[e]);
  }
  __syncthreads();
  if (tid < C_DIM) {
    sums_part[(half * K_CLS + k) * C_DIM + tid] = red[tid];
    sqs_part [(half * K_CLS + k) * C_DIM + tid] = red[C_DIM + tid];
    ovfs_part[(half * K_CLS + k) * C_DIM + tid] = red[2 * C_DIM + tid];
  }
  float* sp = spart + (size_t)(half * K_CLS + k) * (C_DIM * C_DIM);
  #pragma unroll
  for (int mi = 0; mi < 2; ++mi)
    #pragma unroll
    for (int ni = 0; ni < 4; ++ni)
      #pragma unroll
      for (int r = 0; r < 4; ++r) {
        int c = wr * 32 + mi * 16 + ((lane >> 4) << 2) + r;
        int d = wc * 64 + ni * 16 + (lane & 15);
        sp[c * C_DIM + d] = acc[mi][ni][r];
      }
}

// ---------------- per-class analytic corr, off-diag^2 reduction ----------------
__global__ __launch_bounds__(512) void finalize_kernel(const float* __restrict__ spart,
                                                       const float* __restrict__ sums_part,
                                                       const float* __restrict__ sqs_part,
                                                       const float* __restrict__ ovfs_part,
                                                       const int* __restrict__ counts,
                                                       float* __restrict__ numden) {
  __shared__ float m_l[C_DIM], is_l[C_DIM], st_l[C_DIM];
  __shared__ float wred[8];
  int k = blockIdx.x, tid = threadIdx.x;
  int count = counts[k];
  float Tf = (float)(count < PAD_R ? count : PAD_R);
  if (tid < C_DIM) {
    float s_tr = sums_part[k * C_DIM + tid] + sums_part[(K_CLS + k) * C_DIM + tid];
    float osum = ovfs_part[k * C_DIM + tid] + ovfs_part[(K_CLS + k) * C_DIM + tid];
    float fsum = s_tr + osum;
    float fsq  = sqs_part[k * C_DIM + tid] + sqs_part[(K_CLS + k) * C_DIM + tid];
    float cf = (float)count;
    float m = fsum / fmaxf(cf, 1.f);
    float var = (fsq - cf * m * m) / fmaxf(cf - 1.f, 1.f);
    m_l[tid] = m;
    is_l[tid] = rsqrtf(var + EPS_F);
    st_l[tid] = s_tr;
  }
  __syncthreads();
  const float* S0 = spart + (size_t)k * (C_DIM * C_DIM);
  const float* S1 = spart + (size_t)(K_CLS + k) * (C_DIM * C_DIM);
  float local = 0.f;
  for (int e4 = tid * 4; e4 < C_DIM * C_DIM; e4 += 512 * 4) {
    int c = e4 >> 7, d0 = e4 & 127;
    f32x4 s0 = *(const f32x4*)(S0 + e4);
    f32x4 s1 = *(const f32x4*)(S1 + e4);
    #pragma unroll
    for (int e = 0; e < 4; ++e) {
      int d = d0 + e;
      float S = s0[e] + s1[e];
      float corr = is_l[c] * is_l[d] *
                   (S - m_l[c] * st_l[d] - m_l[d] * st_l[c] + Tf * m_l[c] * m_l[d]);
      if (c != d) local += corr * corr;
    }
  }
  for (int off = 32; off > 0; off >>= 1) local += __shfl_down(local, off);
  int lane = tid & 63, wid = tid >> 6;
  if (lane == 0) wred[wid] = local;
  __syncthreads();
  if (tid == 0 && count > 1) {
    float tot = 0.f;
    #pragma unroll
    for (int i = 0; i < 8; ++i) tot += wred[i];
    atomicAdd(&numden[0], tot * (1.f / (float)(C_DIM * (C_DIM - 1))));
    atomicAdd(&numden[1], (float)count);
  }
}

__global__ void div_kernel(const float* __restrict__ numden, float* __restrict__ out) {
  if (threadIdx.x == 0 && blockIdx.x == 0)
    out[0] = numden[1] > 0.f ? numden[0] / numden[1] : 0.f;
}

// ---------------- workspace layout ----------------
// [0,256)            numden
// [256, +128K)       hist
// [131328, +512)     counts
// [132096, +2M)      ord (128 * 4096 * 4)
// [2229248, +128K)   sums_part
// [2360320, +128K)   sqs_part
// [2491392, +128K)   ovfs_part
// [2622464, +16M)    spart           total ~19.4 MB
extern "C" void kernel_launch(void* const* d_in, const int* in_sizes, int n_in,
                              void* d_out, int out_size, void* d_ws, size_t ws_size,
                              hipStream_t stream) {
  (void)in_sizes; (void)n_in; (void)out_size; (void)ws_size;
  const float* x = (const float*)d_in[0];
  const int*   y = (const int*)d_in[1];
  float* out = (float*)d_out;
  char* ws = (char*)d_ws;

  float* numden    = (float*)(ws + 0);
  int*   hist      = (int*)(ws + 256);
  int*   counts    = (int*)(ws + 131328);
  int*   ord       = (int*)(ws + 132096);
  float* sums_part = (float*)(ws + 2229248);
  float* sqs_part  = (float*)(ws + 2360320);
  float* ovfs_part = (float*)(ws + 2491392);
  float* spart     = (float*)(ws + 2622464);

  (void)hipMemsetAsync(numden, 0, 256, stream);

  hist_kernel<<<G_CHUNKS, 256, 0, stream>>>(y, hist);
  scan_kernel<<<K_CLS, 256, 0, stream>>>(hist, counts);
  rank_kernel<<<G_CHUNKS, 256, 0, stream>>>(y, hist, ord);
  gemm_kernel<<<2 * K_CLS, 512, 0, stream>>>(x, ord, counts, spart, sums_part, sqs_part,
                                             ovfs_part);
  finalize_kernel<<<K_CLS, 512, 0, stream>>>(spart, sums_part, sqs_part, ovfs_part,
                                             counts, numden);
  div_kernel<<<1, 64, 0, stream>>>(numden, out);
}